// Round 4
// baseline (963.226 us; speedup 1.0000x reference)
//
#include <hip/hip_runtime.h>

#define NB 16
#define NN 2048
#define NP 512
#define NS 32
#define NC 64

typedef _Float16 f16x8 __attribute__((ext_vector_type(8)));
typedef _Float16 f16x4 __attribute__((ext_vector_type(4)));
typedef float f32x4 __attribute__((ext_vector_type(4)));

// d2 with explicit rounding (no FMA contraction) to bit-match the reference
__device__ __forceinline__ float sqdist(float dx, float dy, float dz) {
  return __fadd_rn(__fadd_rn(__fmul_rn(dx, dx), __fmul_rn(dy, dy)), __fmul_rn(dz, dz));
}

template <int CTRL>
__device__ __forceinline__ unsigned long long dppmax(unsigned long long k) {
  unsigned lo = (unsigned)k, hi = (unsigned)(k >> 32);
  unsigned lo2 = (unsigned)__builtin_amdgcn_update_dpp(0, (int)lo, CTRL, 0xf, 0xf, true);
  unsigned hi2 = (unsigned)__builtin_amdgcn_update_dpp(0, (int)hi, CTRL, 0xf, 0xf, true);
  unsigned long long k2 = ((unsigned long long)hi2 << 32) | lo2;
  return k > k2 ? k : k2;
}

// ---------------------------------------------------------------------------
// prep: features (B,C,N) f32 -> featF (B,N,C) f16; xyz -> xyzT (B,N,4) f32
// ---------------------------------------------------------------------------
__global__ __launch_bounds__(256) void prep_kernel(const float* __restrict__ feat,
                                                   const float* __restrict__ xyz,
                                                   _Float16* __restrict__ featF,
                                                   float* __restrict__ xyzT) {
  __shared__ float tile[64][65];
  const int b = blockIdx.x;
  const int n0 = blockIdx.y * 64;
  const int t = threadIdx.x;
  const int g = t >> 6, l = t & 63;
  if (g == 0) {
    int n = n0 + l;
    float4 q;
    q.x = xyz[(size_t)b * 3 * NN + n];
    q.y = xyz[(size_t)b * 3 * NN + NN + n];
    q.z = xyz[(size_t)b * 3 * NN + 2 * NN + n];
    q.w = 0.f;
    ((float4*)xyzT)[(size_t)b * NN + n] = q;
  }
#pragma unroll
  for (int r = 0; r < 16; ++r) {
    int c = g * 16 + r;
    tile[c][l] = feat[((size_t)b * NC + c) * NN + n0 + l];
  }
  __syncthreads();
#pragma unroll
  for (int r = 0; r < 16; ++r) {
    int nl = g * 16 + r;
    featF[((size_t)(b * NN + n0 + nl)) * NC + l] = (_Float16)tile[l][nl];
  }
}

// ---------------------------------------------------------------------------
// weight conversion to f16. W1f is 64x96: cols 0..63 = feature cols (orig 3..66),
// cols 64..66 = xyz cols (orig 0..2), 67..95 = zero.
// ---------------------------------------------------------------------------
__global__ __launch_bounds__(256) void wconv_kernel(const float* __restrict__ W1,
                                                    const float* __restrict__ W2,
                                                    const float* __restrict__ W3,
                                                    _Float16* __restrict__ W1f,
                                                    _Float16* __restrict__ W2f,
                                                    _Float16* __restrict__ W3f) {
  int i = blockIdx.x * 256 + threadIdx.x;
  if (i < 64 * 96) {
    int o = i / 96, k = i - o * 96;
    float v = (k < 64) ? W1[o * 67 + 3 + k] : ((k < 67) ? W1[o * 67 + (k - 64)] : 0.f);
    W1f[i] = (_Float16)v;
  }
  if (i < 128 * 64) W2f[i] = (_Float16)W2[i];
  if (i < 256 * 128) W3f[i] = (_Float16)W3[i];
}

// ---------------------------------------------------------------------------
// FPS v3: 256 threads, 8 pts/thread, launch_bounds(256,1) so all per-point
// state stays in arch VGPRs (round-3 VGPR_Count=32 => AGPR demotion).
// Per-point u64 keys (dist_bits<<32 | NN-1-n) -> depth-3 tree reduce carrying
// (key,x,y,z) -> DPP wave reduce -> LDS merge of 4 waves. Centroids staged in
// LDS, dumped once at the end (no global stores in the serial loop).
// ---------------------------------------------------------------------------
__global__ __launch_bounds__(256, 1) void fps_kernel(const float* __restrict__ xyz,
                                                     float* __restrict__ newxyz) {
  const int b = blockIdx.x, t = threadIdx.x;
  const int w = t >> 6;
  const float* X = xyz + (size_t)b * 3 * NN;
  float px[8], py[8], pz[8], dist[8];
  unsigned lo[8];
#pragma unroll
  for (int j = 0; j < 8; ++j) {
    int n = t + 256 * j;
    px[j] = X[n];
    py[j] = X[NN + n];
    pz[j] = X[2 * NN + n];
    dist[j] = 1e10f;
    lo[j] = (unsigned)(NN - 1 - n);
  }
  __shared__ __align__(16) unsigned cnd[2][4][8];
  __shared__ float cst[3][NP];
  float cx = X[0], cy = X[NN], cz = X[2 * NN];
  for (int i = 0; i < NP; ++i) {
    if (t == 0) {
      cst[0][i] = cx;
      cst[1][i] = cy;
      cst[2][i] = cz;
    }
    // update dists (independent across points; pipelined)
    float nd[8];
#pragma unroll
    for (int j = 0; j < 8; ++j) {
      float d2 = sqdist(px[j] - cx, py[j] - cy, pz[j] - cz);
      nd[j] = fminf(dist[j], d2);
      dist[j] = nd[j];
    }
    // per-point keys + xyz; depth-3 tree max (all indices compile-time)
    unsigned long long k[8];
    float sx[8], sy[8], sz[8];
#pragma unroll
    for (int j = 0; j < 8; ++j) {
      k[j] = ((unsigned long long)__float_as_uint(nd[j]) << 32) | lo[j];
      sx[j] = px[j];
      sy[j] = py[j];
      sz[j] = pz[j];
    }
#pragma unroll
    for (int st = 1; st < 8; st <<= 1) {
#pragma unroll
      for (int j = 0; j < 8; j += 2 * st) {
        bool gt = k[j + st] > k[j];
        k[j] = gt ? k[j + st] : k[j];
        sx[j] = gt ? sx[j + st] : sx[j];
        sy[j] = gt ? sy[j + st] : sy[j];
        sz[j] = gt ? sz[j + st] : sz[j];
      }
    }
    const unsigned long long loc = k[0];
    unsigned long long red = loc;
    red = dppmax<0x111>(red);  // row_shr:1
    red = dppmax<0x112>(red);  // row_shr:2
    red = dppmax<0x114>(red);  // row_shr:4
    red = dppmax<0x118>(red);  // row_shr:8
    red = dppmax<0x142>(red);  // row_bcast:15
    red = dppmax<0x143>(red);  // row_bcast:31  -> lane 63 has wave max
    unsigned wlo = (unsigned)__builtin_amdgcn_readlane((int)(unsigned)(red & 0xffffffffull), 63);
    unsigned whi = (unsigned)__builtin_amdgcn_readlane((int)(unsigned)(red >> 32), 63);
    const int buf = i & 1;
    if (loc == ((((unsigned long long)whi) << 32) | wlo)) {  // exactly one lane/wave
      unsigned* c = cnd[buf][w];
      c[0] = wlo;
      c[1] = whi;
      c[2] = __float_as_uint(sx[0]);
      c[3] = __float_as_uint(sy[0]);
      c[4] = __float_as_uint(sz[0]);
    }
    __syncthreads();
    uint4 q0 = *(const uint4*)cnd[buf][0];
    unsigned z0 = cnd[buf][0][4];
    uint4 q1 = *(const uint4*)cnd[buf][1];
    unsigned z1 = cnd[buf][1][4];
    uint4 q2 = *(const uint4*)cnd[buf][2];
    unsigned z2 = cnd[buf][2][4];
    uint4 q3 = *(const uint4*)cnd[buf][3];
    unsigned z3 = cnd[buf][3][4];
    unsigned long long k0 = ((unsigned long long)q0.y << 32) | q0.x;
    unsigned long long k1 = ((unsigned long long)q1.y << 32) | q1.x;
    unsigned long long k2 = ((unsigned long long)q2.y << 32) | q2.x;
    unsigned long long k3 = ((unsigned long long)q3.y << 32) | q3.x;
    if (k1 > k0) { k0 = k1; q0 = q1; z0 = z1; }
    if (k3 > k2) { k2 = k3; q2 = q3; z2 = z3; }
    if (k2 > k0) { k0 = k2; q0 = q2; z0 = z2; }
    cx = __uint_as_float(q0.z);
    cy = __uint_as_float(q0.w);
    cz = __uint_as_float(z0);
  }
  __syncthreads();
  for (int i = t; i < NP; i += 256) {
    newxyz[b * 3 * NP + i] = cst[0][i];
    newxyz[b * 3 * NP + NP + i] = cst[1][i];
    newxyz[b * 3 * NP + 2 * NP + i] = cst[2][i];
  }
}

// ---------------------------------------------------------------------------
// Ball query (unchanged, bit-exact).
// ---------------------------------------------------------------------------
__global__ __launch_bounds__(256) void ball_kernel(const float* __restrict__ xyz,
                                                   const float* __restrict__ newxyz,
                                                   int* __restrict__ idx) {
  const int b = blockIdx.x;
  const int s = blockIdx.y * 4 + (threadIdx.x >> 6);
  const int lane = threadIdx.x & 63;
  const float* X = xyz + (size_t)b * 3 * NN;
  const float cx = newxyz[b * 3 * NP + s];
  const float cy = newxyz[b * 3 * NP + NP + s];
  const float cz = newxyz[b * 3 * NP + 2 * NP + s];
  int* row = idx + ((size_t)(b * NP + s)) * NS;
  const float r2 = (float)(0.2 * 0.2);
  int total = 0, first = 0;
  bool havefirst = false;
  for (int c0 = 0; c0 < NN; c0 += 64) {
    int n = c0 + lane;
    float d2 = sqdist(X[n] - cx, X[NN + n] - cy, X[2 * NN + n] - cz);
    bool hit = d2 < r2;
    unsigned long long mask = __ballot(hit);
    if (!havefirst && mask) {
      first = c0 + __builtin_ctzll(mask);
      havefirst = true;
    }
    if (hit) {
      int pos = total + (int)__popcll(mask & ((1ull << lane) - 1ull));
      if (pos < NS) row[pos] = n;
    }
    total += (int)__popcll(mask);
    if (total >= NS) break;
  }
  if (total < NS && lane >= total && lane < NS) row[lane] = first;
}

// ---------------------------------------------------------------------------
// MFMA MLP (unchanged from round 3): 128 cols/block (4 s), f16 activations in
// LDS [col][k], waves split output rows, fused maxpool, fp32 accumulate.
// ---------------------------------------------------------------------------
#define HSTR 104   // hT stride in f16 (96 padded)
#define A1STR 72   // a1 stride (64 padded)
#define A2STR 136  // a2 stride (128 padded)
#define A1OFF 17408

__global__ __launch_bounds__(256) void mlp_kernel(
    const float* __restrict__ xyzT, const _Float16* __restrict__ featF,
    const int* __restrict__ idx, const float* __restrict__ newxyz,
    const _Float16* __restrict__ W1f, const float* __restrict__ b1,
    const _Float16* __restrict__ W2f, const float* __restrict__ b2,
    const _Float16* __restrict__ W3f, const float* __restrict__ b3, float* __restrict__ out) {
  __shared__ _Float16 smem[17408 + 9216];  // 52 KB: h/a2 alias region + a1
  _Float16* hT = smem;
  _Float16* a1T = smem + A1OFF;
  const int b = blockIdx.x;
  const int s0 = blockIdx.y * 4;
  const int t = threadIdx.x;
  const int lane = t & 63, w = t >> 6;

  // ---- gather: hT[128 cols][96 k] (k: 0..63 feat, 64..66 relxyz, 67..95 zero)
  {
    const int col = t & 127, hf = t >> 7;
    const int s = s0 + (col >> 5), k = col & 31;
    const int n = idx[((size_t)(b * NP + s)) * NS + k];
    const _Float16* F = featF + (size_t)(b * NN + n) * NC;
#pragma unroll
    for (int j = 0; j < 4; ++j) {
      int p = hf * 4 + j;
      *(f16x8*)(&hT[col * HSTR + p * 8]) = *(const f16x8*)(F + p * 8);
    }
    if (hf == 0) {
      float4 pnt = ((const float4*)xyzT)[(size_t)b * NN + n];
      float cx = newxyz[b * 3 * NP + s];
      float cy = newxyz[b * 3 * NP + NP + s];
      float cz = newxyz[b * 3 * NP + 2 * NP + s];
      f16x8 v = {};
      v[0] = (_Float16)(pnt.x - cx);
      v[1] = (_Float16)(pnt.y - cy);
      v[2] = (_Float16)(pnt.z - cz);
      *(f16x8*)(&hT[col * HSTR + 64]) = v;
    } else {
      f16x8 z = {};
      *(f16x8*)(&hT[col * HSTR + 72]) = z;
      *(f16x8*)(&hT[col * HSTR + 80]) = z;
      *(f16x8*)(&hT[col * HSTR + 88]) = z;
    }
  }
  __syncthreads();

  const int cl = lane & 15;  // A row / B col within tile
  const int kg = lane >> 4;  // k-group; D row group

  // ---- layer 1: K=96, O=64; wave w owns rows w*16..+15
  {
    f32x4 acc[8];
    {
      f32x4 bb = *(const f32x4*)(b1 + w * 16 + kg * 4);
#pragma unroll
      for (int ct = 0; ct < 8; ++ct) acc[ct] = bb;
    }
#pragma unroll
    for (int ks = 0; ks < 3; ++ks) {
      f16x8 A = *(const f16x8*)(W1f + (w * 16 + cl) * 96 + ks * 32 + kg * 8);
#pragma unroll
      for (int ct = 0; ct < 8; ++ct) {
        f16x8 B = *(const f16x8*)(&hT[(ct * 16 + cl) * HSTR + ks * 32 + kg * 8]);
        acc[ct] = __builtin_amdgcn_mfma_f32_16x16x32_f16(A, B, acc[ct], 0, 0, 0);
      }
    }
#pragma unroll
    for (int ct = 0; ct < 8; ++ct) {
      f16x4 v;
#pragma unroll
      for (int i2 = 0; i2 < 4; ++i2) v[i2] = (_Float16)fmaxf(acc[ct][i2], 0.f);
      *(f16x4*)(&a1T[(ct * 16 + cl) * A1STR + w * 16 + kg * 4]) = v;
    }
  }
  __syncthreads();

  // ---- layer 2: K=64, O=128; wave w owns rows w*32..+31 (a2 aliases h)
  {
    f32x4 acc[2][8];
#pragma unroll
    for (int r = 0; r < 2; ++r) {
      f32x4 bb = *(const f32x4*)(b2 + w * 32 + r * 16 + kg * 4);
#pragma unroll
      for (int ct = 0; ct < 8; ++ct) acc[r][ct] = bb;
    }
#pragma unroll
    for (int ks = 0; ks < 2; ++ks) {
      f16x8 A0 = *(const f16x8*)(W2f + (w * 32 + cl) * 64 + ks * 32 + kg * 8);
      f16x8 A1 = *(const f16x8*)(W2f + (w * 32 + 16 + cl) * 64 + ks * 32 + kg * 8);
#pragma unroll
      for (int ct = 0; ct < 8; ++ct) {
        f16x8 B = *(const f16x8*)(&a1T[(ct * 16 + cl) * A1STR + ks * 32 + kg * 8]);
        acc[0][ct] = __builtin_amdgcn_mfma_f32_16x16x32_f16(A0, B, acc[0][ct], 0, 0, 0);
        acc[1][ct] = __builtin_amdgcn_mfma_f32_16x16x32_f16(A1, B, acc[1][ct], 0, 0, 0);
      }
    }
#pragma unroll
    for (int r = 0; r < 2; ++r)
#pragma unroll
      for (int ct = 0; ct < 8; ++ct) {
        f16x4 v;
#pragma unroll
        for (int i2 = 0; i2 < 4; ++i2) v[i2] = (_Float16)fmaxf(acc[r][ct][i2], 0.f);
        *(f16x4*)(&hT[(ct * 16 + cl) * A2STR + w * 32 + r * 16 + kg * 4]) = v;
      }
  }
  __syncthreads();

  // ---- layer 3: K=128, O=256; wave w owns rows w*64..+63; fused maxpool
  float* out2 = out + NB * 3 * NP;
#pragma unroll
  for (int rh = 0; rh < 2; ++rh) {
    f32x4 acc[2][8];
#pragma unroll
    for (int r = 0; r < 2; ++r) {
      f32x4 bb = *(const f32x4*)(b3 + w * 64 + rh * 32 + r * 16 + kg * 4);
#pragma unroll
      for (int ct = 0; ct < 8; ++ct) acc[r][ct] = bb;
    }
#pragma unroll
    for (int ks = 0; ks < 4; ++ks) {
      f16x8 A0 = *(const f16x8*)(W3f + (w * 64 + rh * 32 + cl) * 128 + ks * 32 + kg * 8);
      f16x8 A1 = *(const f16x8*)(W3f + (w * 64 + rh * 32 + 16 + cl) * 128 + ks * 32 + kg * 8);
#pragma unroll
      for (int ct = 0; ct < 8; ++ct) {
        f16x8 B = *(const f16x8*)(&hT[(ct * 16 + cl) * A2STR + ks * 32 + kg * 8]);
        acc[0][ct] = __builtin_amdgcn_mfma_f32_16x16x32_f16(A0, B, acc[0][ct], 0, 0, 0);
        acc[1][ct] = __builtin_amdgcn_mfma_f32_16x16x32_f16(A1, B, acc[1][ct], 0, 0, 0);
      }
    }
#pragma unroll
    for (int r = 0; r < 2; ++r)
#pragma unroll
      for (int sl = 0; sl < 4; ++sl) {
        float vv[4];
#pragma unroll
        for (int i2 = 0; i2 < 4; ++i2) {
          float m0 = fmaxf(acc[r][sl * 2][i2], 0.f);
          float m1 = fmaxf(acc[r][sl * 2 + 1][i2], 0.f);
          float mv = fmaxf(m0, m1);
          mv = fmaxf(mv, __shfl_xor(mv, 1, 64));
          mv = fmaxf(mv, __shfl_xor(mv, 2, 64));
          mv = fmaxf(mv, __shfl_xor(mv, 4, 64));
          mv = fmaxf(mv, __shfl_xor(mv, 8, 64));
          vv[i2] = mv;
        }
        if (cl == 0) {
          int ob = w * 64 + rh * 32 + r * 16 + kg * 4;
#pragma unroll
          for (int i2 = 0; i2 < 4; ++i2)
            out2[((size_t)(b * 256 + ob + i2)) * NP + s0 + sl] = vv[i2];
        }
      }
  }
}

extern "C" void kernel_launch(void* const* d_in, const int* in_sizes, int n_in, void* d_out,
                              int out_size, void* d_ws, size_t ws_size, hipStream_t stream) {
  const float* xyz = (const float*)d_in[0];
  const float* feat = (const float*)d_in[1];
  const float* W1 = (const float*)d_in[2];
  const float* b1 = (const float*)d_in[3];
  const float* W2 = (const float*)d_in[4];
  const float* b2 = (const float*)d_in[5];
  const float* W3 = (const float*)d_in[6];
  const float* b3 = (const float*)d_in[7];
  float* out = (float*)d_out;
  char* ws = (char*)d_ws;
  float* xyzT = (float*)ws;                    // 512 KB
  _Float16* featF = (_Float16*)(ws + 524288);  // 4 MB
  int* idx = (int*)(ws + 4718592);             // 1 MB
  _Float16* W1f = (_Float16*)(ws + 5767168);   // 12 KB
  _Float16* W2f = (_Float16*)(ws + 5779456);   // 16 KB
  _Float16* W3f = (_Float16*)(ws + 5795840);   // 64 KB

  hipLaunchKernelGGL(prep_kernel, dim3(NB, 32), dim3(256), 0, stream, feat, xyz, featF, xyzT);
  hipLaunchKernelGGL(wconv_kernel, dim3(128), dim3(256), 0, stream, W1, W2, W3, W1f, W2f, W3f);
  hipLaunchKernelGGL(fps_kernel, dim3(NB), dim3(256), 0, stream, xyz, out);
  hipLaunchKernelGGL(ball_kernel, dim3(NB, 128), dim3(256), 0, stream, xyz, out, idx);
  hipLaunchKernelGGL(mlp_kernel, dim3(NB, 128), dim3(256), 0, stream, xyzT, featF, idx, out, W1f,
                     b1, W2f, b2, W3f, b3, out);
}

// Round 5
// 494.668 us; speedup vs baseline: 1.9472x; 1.9472x over previous
//
#include <hip/hip_runtime.h>

#define NB 16
#define NN 2048
#define NP 512
#define NS 32
#define NC 64

typedef _Float16 f16x8 __attribute__((ext_vector_type(8)));
typedef _Float16 f16x4 __attribute__((ext_vector_type(4)));
typedef float f32x4 __attribute__((ext_vector_type(4)));

// d2 with explicit rounding (no FMA contraction) to bit-match the reference
__device__ __forceinline__ float sqdist(float dx, float dy, float dz) {
  return __fadd_rn(__fadd_rn(__fmul_rn(dx, dx), __fmul_rn(dy, dy)), __fmul_rn(dz, dz));
}

template <int CTRL>
__device__ __forceinline__ unsigned long long dppmax(unsigned long long k) {
  unsigned lo = (unsigned)k, hi = (unsigned)(k >> 32);
  unsigned lo2 = (unsigned)__builtin_amdgcn_update_dpp(0, (int)lo, CTRL, 0xf, 0xf, true);
  unsigned hi2 = (unsigned)__builtin_amdgcn_update_dpp(0, (int)hi, CTRL, 0xf, 0xf, true);
  unsigned long long k2 = ((unsigned long long)hi2 << 32) | lo2;
  return k > k2 ? k : k2;
}

// ---------------------------------------------------------------------------
// prep: features (B,C,N) f32 -> featF (B,N,C) f16; xyz -> xyzT (B,N,4) f32
// ---------------------------------------------------------------------------
__global__ __launch_bounds__(256) void prep_kernel(const float* __restrict__ feat,
                                                   const float* __restrict__ xyz,
                                                   _Float16* __restrict__ featF,
                                                   float* __restrict__ xyzT) {
  __shared__ float tile[64][65];
  const int b = blockIdx.x;
  const int n0 = blockIdx.y * 64;
  const int t = threadIdx.x;
  const int g = t >> 6, l = t & 63;
  if (g == 0) {
    int n = n0 + l;
    float4 q;
    q.x = xyz[(size_t)b * 3 * NN + n];
    q.y = xyz[(size_t)b * 3 * NN + NN + n];
    q.z = xyz[(size_t)b * 3 * NN + 2 * NN + n];
    q.w = 0.f;
    ((float4*)xyzT)[(size_t)b * NN + n] = q;
  }
#pragma unroll
  for (int r = 0; r < 16; ++r) {
    int c = g * 16 + r;
    tile[c][l] = feat[((size_t)b * NC + c) * NN + n0 + l];
  }
  __syncthreads();
#pragma unroll
  for (int r = 0; r < 16; ++r) {
    int nl = g * 16 + r;
    featF[((size_t)(b * NN + n0 + nl)) * NC + l] = (_Float16)tile[l][nl];
  }
}

// ---------------------------------------------------------------------------
// weight conversion to f16. W1f is 64x96: cols 0..63 = feature cols (orig 3..66),
// cols 64..66 = xyz cols (orig 0..2), 67..95 = zero.
// ---------------------------------------------------------------------------
__global__ __launch_bounds__(256) void wconv_kernel(const float* __restrict__ W1,
                                                    const float* __restrict__ W2,
                                                    const float* __restrict__ W3,
                                                    _Float16* __restrict__ W1f,
                                                    _Float16* __restrict__ W2f,
                                                    _Float16* __restrict__ W3f) {
  int i = blockIdx.x * 256 + threadIdx.x;
  if (i < 64 * 96) {
    int o = i / 96, k = i - o * 96;
    float v = (k < 64) ? W1[o * 67 + 3 + k] : ((k < 67) ? W1[o * 67 + (k - 64)] : 0.f);
    W1f[i] = (_Float16)v;
  }
  if (i < 128 * 64) W2f[i] = (_Float16)W2[i];
  if (i < 256 * 128) W3f[i] = (_Float16)W3[i];
}

// ---------------------------------------------------------------------------
// FPS v4: ONE WAVE per batch (16 blocks x 64 threads, 32 pts/lane).
// No barriers, no cross-wave traffic. Per-iter: exact dist update (32/lane),
// inline pairwise merge -> u64 tree m[16..1] (all compile-time indices),
// DPP wave max, readlane, centroid via uniform-address ds_read from LDS copy.
// Same u64 key = (dist_bits<<32)|(NN-1-n) -> bit-identical selection.
// ---------------------------------------------------------------------------
__global__ __launch_bounds__(64) void fps_kernel(const float* __restrict__ xyz,
                                                 float* __restrict__ newxyz) {
  const int b = blockIdx.x;
  const int lane = threadIdx.x;
  const float* X = xyz + (size_t)b * 3 * NN;
  __shared__ __align__(16) float4 XL[NN];  // 32 KB
  float px[32], py[32], pz[32], dist[32];
  unsigned klo[32];
#pragma unroll
  for (int j = 0; j < 32; ++j) {
    int n = lane + 64 * j;
    px[j] = X[n];
    py[j] = X[NN + n];
    pz[j] = X[2 * NN + n];
    dist[j] = 1e10f;
    klo[j] = (unsigned)(NN - 1 - n);
    XL[n] = make_float4(px[j], py[j], pz[j], 0.f);
  }
  float cx = X[0], cy = X[NN], cz = X[2 * NN];
  for (int i = 0; i < NP; ++i) {
    if (lane == 0) {
      newxyz[b * 3 * NP + i] = cx;
      newxyz[b * 3 * NP + NP + i] = cy;
      newxyz[b * 3 * NP + 2 * NP + i] = cz;
    }
    // update dists + pairwise first merge level (peak u64 live = 16)
    unsigned long long m[16];
#pragma unroll
    for (int jj = 0; jj < 16; ++jj) {
      const int j0 = 2 * jj, j1 = 2 * jj + 1;
      float d0 = sqdist(px[j0] - cx, py[j0] - cy, pz[j0] - cz);
      float d1 = sqdist(px[j1] - cx, py[j1] - cy, pz[j1] - cz);
      dist[j0] = fminf(dist[j0], d0);
      dist[j1] = fminf(dist[j1], d1);
      unsigned long long ka =
          ((unsigned long long)__float_as_uint(dist[j0]) << 32) | klo[j0];
      unsigned long long kb =
          ((unsigned long long)__float_as_uint(dist[j1]) << 32) | klo[j1];
      m[jj] = ka > kb ? ka : kb;
    }
#pragma unroll
    for (int st = 1; st < 16; st <<= 1)
#pragma unroll
      for (int j = 0; j < 16; j += 2 * st)
        m[j] = m[j] > m[j + st] ? m[j] : m[j + st];
    unsigned long long red = m[0];
    red = dppmax<0x111>(red);  // row_shr:1
    red = dppmax<0x112>(red);  // row_shr:2
    red = dppmax<0x114>(red);  // row_shr:4
    red = dppmax<0x118>(red);  // row_shr:8
    red = dppmax<0x142>(red);  // row_bcast:15
    red = dppmax<0x143>(red);  // row_bcast:31  -> lane 63 has wave max
    unsigned wlo = (unsigned)__builtin_amdgcn_readlane((int)(unsigned)(red & 0xffffffffull), 63);
    const int n = NN - 1 - (int)wlo;
    float4 c = XL[n];  // uniform address -> LDS broadcast
    cx = c.x;
    cy = c.y;
    cz = c.z;
  }
}

// ---------------------------------------------------------------------------
// Ball query (unchanged, bit-exact).
// ---------------------------------------------------------------------------
__global__ __launch_bounds__(256) void ball_kernel(const float* __restrict__ xyz,
                                                   const float* __restrict__ newxyz,
                                                   int* __restrict__ idx) {
  const int b = blockIdx.x;
  const int s = blockIdx.y * 4 + (threadIdx.x >> 6);
  const int lane = threadIdx.x & 63;
  const float* X = xyz + (size_t)b * 3 * NN;
  const float cx = newxyz[b * 3 * NP + s];
  const float cy = newxyz[b * 3 * NP + NP + s];
  const float cz = newxyz[b * 3 * NP + 2 * NP + s];
  int* row = idx + ((size_t)(b * NP + s)) * NS;
  const float r2 = (float)(0.2 * 0.2);
  int total = 0, first = 0;
  bool havefirst = false;
  for (int c0 = 0; c0 < NN; c0 += 64) {
    int n = c0 + lane;
    float d2 = sqdist(X[n] - cx, X[NN + n] - cy, X[2 * NN + n] - cz);
    bool hit = d2 < r2;
    unsigned long long mask = __ballot(hit);
    if (!havefirst && mask) {
      first = c0 + __builtin_ctzll(mask);
      havefirst = true;
    }
    if (hit) {
      int pos = total + (int)__popcll(mask & ((1ull << lane) - 1ull));
      if (pos < NS) row[pos] = n;
    }
    total += (int)__popcll(mask);
    if (total >= NS) break;
  }
  if (total < NS && lane >= total && lane < NS) row[lane] = first;
}

// ---------------------------------------------------------------------------
// MFMA MLP (unchanged): 128 cols/block (4 s), f16 activations in LDS [col][k],
// waves split output rows, fused maxpool, fp32 accumulate.
// ---------------------------------------------------------------------------
#define HSTR 104   // hT stride in f16 (96 padded)
#define A1STR 72   // a1 stride (64 padded)
#define A2STR 136  // a2 stride (128 padded)
#define A1OFF 17408

__global__ __launch_bounds__(256) void mlp_kernel(
    const float* __restrict__ xyzT, const _Float16* __restrict__ featF,
    const int* __restrict__ idx, const float* __restrict__ newxyz,
    const _Float16* __restrict__ W1f, const float* __restrict__ b1,
    const _Float16* __restrict__ W2f, const float* __restrict__ b2,
    const _Float16* __restrict__ W3f, const float* __restrict__ b3, float* __restrict__ out) {
  __shared__ _Float16 smem[17408 + 9216];  // 52 KB: h/a2 alias region + a1
  _Float16* hT = smem;
  _Float16* a1T = smem + A1OFF;
  const int b = blockIdx.x;
  const int s0 = blockIdx.y * 4;
  const int t = threadIdx.x;
  const int lane = t & 63, w = t >> 6;

  // ---- gather: hT[128 cols][96 k] (k: 0..63 feat, 64..66 relxyz, 67..95 zero)
  {
    const int col = t & 127, hf = t >> 7;
    const int s = s0 + (col >> 5), k = col & 31;
    const int n = idx[((size_t)(b * NP + s)) * NS + k];
    const _Float16* F = featF + (size_t)(b * NN + n) * NC;
#pragma unroll
    for (int j = 0; j < 4; ++j) {
      int p = hf * 4 + j;
      *(f16x8*)(&hT[col * HSTR + p * 8]) = *(const f16x8*)(F + p * 8);
    }
    if (hf == 0) {
      float4 pnt = ((const float4*)xyzT)[(size_t)b * NN + n];
      float cx = newxyz[b * 3 * NP + s];
      float cy = newxyz[b * 3 * NP + NP + s];
      float cz = newxyz[b * 3 * NP + 2 * NP + s];
      f16x8 v = {};
      v[0] = (_Float16)(pnt.x - cx);
      v[1] = (_Float16)(pnt.y - cy);
      v[2] = (_Float16)(pnt.z - cz);
      *(f16x8*)(&hT[col * HSTR + 64]) = v;
    } else {
      f16x8 z = {};
      *(f16x8*)(&hT[col * HSTR + 72]) = z;
      *(f16x8*)(&hT[col * HSTR + 80]) = z;
      *(f16x8*)(&hT[col * HSTR + 88]) = z;
    }
  }
  __syncthreads();

  const int cl = lane & 15;  // A row / B col within tile
  const int kg = lane >> 4;  // k-group; D row group

  // ---- layer 1: K=96, O=64; wave w owns rows w*16..+15
  {
    f32x4 acc[8];
    {
      f32x4 bb = *(const f32x4*)(b1 + w * 16 + kg * 4);
#pragma unroll
      for (int ct = 0; ct < 8; ++ct) acc[ct] = bb;
    }
#pragma unroll
    for (int ks = 0; ks < 3; ++ks) {
      f16x8 A = *(const f16x8*)(W1f + (w * 16 + cl) * 96 + ks * 32 + kg * 8);
#pragma unroll
      for (int ct = 0; ct < 8; ++ct) {
        f16x8 B = *(const f16x8*)(&hT[(ct * 16 + cl) * HSTR + ks * 32 + kg * 8]);
        acc[ct] = __builtin_amdgcn_mfma_f32_16x16x32_f16(A, B, acc[ct], 0, 0, 0);
      }
    }
#pragma unroll
    for (int ct = 0; ct < 8; ++ct) {
      f16x4 v;
#pragma unroll
      for (int i2 = 0; i2 < 4; ++i2) v[i2] = (_Float16)fmaxf(acc[ct][i2], 0.f);
      *(f16x4*)(&a1T[(ct * 16 + cl) * A1STR + w * 16 + kg * 4]) = v;
    }
  }
  __syncthreads();

  // ---- layer 2: K=64, O=128; wave w owns rows w*32..+31 (a2 aliases h)
  {
    f32x4 acc[2][8];
#pragma unroll
    for (int r = 0; r < 2; ++r) {
      f32x4 bb = *(const f32x4*)(b2 + w * 32 + r * 16 + kg * 4);
#pragma unroll
      for (int ct = 0; ct < 8; ++ct) acc[r][ct] = bb;
    }
#pragma unroll
    for (int ks = 0; ks < 2; ++ks) {
      f16x8 A0 = *(const f16x8*)(W2f + (w * 32 + cl) * 64 + ks * 32 + kg * 8);
      f16x8 A1 = *(const f16x8*)(W2f + (w * 32 + 16 + cl) * 64 + ks * 32 + kg * 8);
#pragma unroll
      for (int ct = 0; ct < 8; ++ct) {
        f16x8 B = *(const f16x8*)(&a1T[(ct * 16 + cl) * A1STR + ks * 32 + kg * 8]);
        acc[0][ct] = __builtin_amdgcn_mfma_f32_16x16x32_f16(A0, B, acc[0][ct], 0, 0, 0);
        acc[1][ct] = __builtin_amdgcn_mfma_f32_16x16x32_f16(A1, B, acc[1][ct], 0, 0, 0);
      }
    }
#pragma unroll
    for (int r = 0; r < 2; ++r)
#pragma unroll
      for (int ct = 0; ct < 8; ++ct) {
        f16x4 v;
#pragma unroll
        for (int i2 = 0; i2 < 4; ++i2) v[i2] = (_Float16)fmaxf(acc[r][ct][i2], 0.f);
        *(f16x4*)(&hT[(ct * 16 + cl) * A2STR + w * 32 + r * 16 + kg * 4]) = v;
      }
  }
  __syncthreads();

  // ---- layer 3: K=128, O=256; wave w owns rows w*64..+63; fused maxpool
  float* out2 = out + NB * 3 * NP;
#pragma unroll
  for (int rh = 0; rh < 2; ++rh) {
    f32x4 acc[2][8];
#pragma unroll
    for (int r = 0; r < 2; ++r) {
      f32x4 bb = *(const f32x4*)(b3 + w * 64 + rh * 32 + r * 16 + kg * 4);
#pragma unroll
      for (int ct = 0; ct < 8; ++ct) acc[r][ct] = bb;
    }
#pragma unroll
    for (int ks = 0; ks < 4; ++ks) {
      f16x8 A0 = *(const f16x8*)(W3f + (w * 64 + rh * 32 + cl) * 128 + ks * 32 + kg * 8);
      f16x8 A1 = *(const f16x8*)(W3f + (w * 64 + rh * 32 + 16 + cl) * 128 + ks * 32 + kg * 8);
#pragma unroll
      for (int ct = 0; ct < 8; ++ct) {
        f16x8 B = *(const f16x8*)(&hT[(ct * 16 + cl) * A2STR + ks * 32 + kg * 8]);
        acc[0][ct] = __builtin_amdgcn_mfma_f32_16x16x32_f16(A0, B, acc[0][ct], 0, 0, 0);
        acc[1][ct] = __builtin_amdgcn_mfma_f32_16x16x32_f16(A1, B, acc[1][ct], 0, 0, 0);
      }
    }
#pragma unroll
    for (int r = 0; r < 2; ++r)
#pragma unroll
      for (int sl = 0; sl < 4; ++sl) {
        float vv[4];
#pragma unroll
        for (int i2 = 0; i2 < 4; ++i2) {
          float m0 = fmaxf(acc[r][sl * 2][i2], 0.f);
          float m1 = fmaxf(acc[r][sl * 2 + 1][i2], 0.f);
          float mv = fmaxf(m0, m1);
          mv = fmaxf(mv, __shfl_xor(mv, 1, 64));
          mv = fmaxf(mv, __shfl_xor(mv, 2, 64));
          mv = fmaxf(mv, __shfl_xor(mv, 4, 64));
          mv = fmaxf(mv, __shfl_xor(mv, 8, 64));
          vv[i2] = mv;
        }
        if (cl == 0) {
          int ob = w * 64 + rh * 32 + r * 16 + kg * 4;
#pragma unroll
          for (int i2 = 0; i2 < 4; ++i2)
            out2[((size_t)(b * 256 + ob + i2)) * NP + s0 + sl] = vv[i2];
        }
      }
  }
}

extern "C" void kernel_launch(void* const* d_in, const int* in_sizes, int n_in, void* d_out,
                              int out_size, void* d_ws, size_t ws_size, hipStream_t stream) {
  const float* xyz = (const float*)d_in[0];
  const float* feat = (const float*)d_in[1];
  const float* W1 = (const float*)d_in[2];
  const float* b1 = (const float*)d_in[3];
  const float* W2 = (const float*)d_in[4];
  const float* b2 = (const float*)d_in[5];
  const float* W3 = (const float*)d_in[6];
  const float* b3 = (const float*)d_in[7];
  float* out = (float*)d_out;
  char* ws = (char*)d_ws;
  float* xyzT = (float*)ws;                    // 512 KB
  _Float16* featF = (_Float16*)(ws + 524288);  // 4 MB
  int* idx = (int*)(ws + 4718592);             // 1 MB
  _Float16* W1f = (_Float16*)(ws + 5767168);   // 12 KB
  _Float16* W2f = (_Float16*)(ws + 5779456);   // 16 KB
  _Float16* W3f = (_Float16*)(ws + 5795840);   // 64 KB

  hipLaunchKernelGGL(prep_kernel, dim3(NB, 32), dim3(256), 0, stream, feat, xyz, featF, xyzT);
  hipLaunchKernelGGL(wconv_kernel, dim3(128), dim3(256), 0, stream, W1, W2, W3, W1f, W2f, W3f);
  hipLaunchKernelGGL(fps_kernel, dim3(NB), dim3(64), 0, stream, xyz, out);
  hipLaunchKernelGGL(ball_kernel, dim3(NB, 128), dim3(256), 0, stream, xyz, out, idx);
  hipLaunchKernelGGL(mlp_kernel, dim3(NB, 128), dim3(256), 0, stream, xyzT, featF, idx, out, W1f,
                     b1, W2f, b2, W3f, b3, out);
}

// Round 6
// 395.925 us; speedup vs baseline: 2.4328x; 1.2494x over previous
//
#include <hip/hip_runtime.h>

#define NB 16
#define NN 2048
#define NP 512
#define NS 32
#define NC 64

typedef _Float16 f16x8 __attribute__((ext_vector_type(8)));
typedef _Float16 f16x4 __attribute__((ext_vector_type(4)));
typedef float f32x4 __attribute__((ext_vector_type(4)));
typedef float f32x2 __attribute__((ext_vector_type(2)));

// d2 with explicit rounding (no FMA contraction) to bit-match the reference
__device__ __forceinline__ float sqdist(float dx, float dy, float dz) {
  return __fadd_rn(__fadd_rn(__fmul_rn(dx, dx), __fmul_rn(dy, dy)), __fmul_rn(dz, dz));
}

// packed f32 add/mul via inline asm: separate mul and add instructions, so the
// compiler can never contract them into FMA -> bit-exact vs the reference.
__device__ __forceinline__ f32x2 pk_add(f32x2 a, f32x2 b) {
  f32x2 d;
  asm("v_pk_add_f32 %0, %1, %2" : "=v"(d) : "v"(a), "v"(b));
  return d;
}
__device__ __forceinline__ f32x2 pk_mul(f32x2 a, f32x2 b) {
  f32x2 d;
  asm("v_pk_mul_f32 %0, %1, %2" : "=v"(d) : "v"(a), "v"(b));
  return d;
}

template <int CTRL>
__device__ __forceinline__ float dppmaxf(float m) {
  int t = __builtin_amdgcn_update_dpp(0, __float_as_int(m), CTRL, 0xf, 0xf, true);
  return fmaxf(m, __int_as_float(t));  // 0-fill safe: all values >= 0
}
template <int CTRL>
__device__ __forceinline__ unsigned dppmaxu(unsigned m) {
  int t = __builtin_amdgcn_update_dpp(0, (int)m, CTRL, 0xf, 0xf, true);
  return m > (unsigned)t ? m : (unsigned)t;  // 0-fill safe for max
}

// ---------------------------------------------------------------------------
// prep: features (B,C,N) f32 -> featF (B,N,C) f16; xyz -> xyzT (B,N,4) f32
// ---------------------------------------------------------------------------
__global__ __launch_bounds__(256) void prep_kernel(const float* __restrict__ feat,
                                                   const float* __restrict__ xyz,
                                                   _Float16* __restrict__ featF,
                                                   float* __restrict__ xyzT) {
  __shared__ float tile[64][65];
  const int b = blockIdx.x;
  const int n0 = blockIdx.y * 64;
  const int t = threadIdx.x;
  const int g = t >> 6, l = t & 63;
  if (g == 0) {
    int n = n0 + l;
    float4 q;
    q.x = xyz[(size_t)b * 3 * NN + n];
    q.y = xyz[(size_t)b * 3 * NN + NN + n];
    q.z = xyz[(size_t)b * 3 * NN + 2 * NN + n];
    q.w = 0.f;
    ((float4*)xyzT)[(size_t)b * NN + n] = q;
  }
#pragma unroll
  for (int r = 0; r < 16; ++r) {
    int c = g * 16 + r;
    tile[c][l] = feat[((size_t)b * NC + c) * NN + n0 + l];
  }
  __syncthreads();
#pragma unroll
  for (int r = 0; r < 16; ++r) {
    int nl = g * 16 + r;
    featF[((size_t)(b * NN + n0 + nl)) * NC + l] = (_Float16)tile[l][nl];
  }
}

// ---------------------------------------------------------------------------
// weight conversion to f16. W1f is 64x96: cols 0..63 = feature cols (orig 3..66),
// cols 64..66 = xyz cols (orig 0..2), 67..95 = zero.
// ---------------------------------------------------------------------------
__global__ __launch_bounds__(256) void wconv_kernel(const float* __restrict__ W1,
                                                    const float* __restrict__ W2,
                                                    const float* __restrict__ W3,
                                                    _Float16* __restrict__ W1f,
                                                    _Float16* __restrict__ W2f,
                                                    _Float16* __restrict__ W3f) {
  int i = blockIdx.x * 256 + threadIdx.x;
  if (i < 64 * 96) {
    int o = i / 96, k = i - o * 96;
    float v = (k < 64) ? W1[o * 67 + 3 + k] : ((k < 67) ? W1[o * 67 + (k - 64)] : 0.f);
    W1f[i] = (_Float16)v;
  }
  if (i < 128 * 64) W2f[i] = (_Float16)W2[i];
  if (i < 256 * 128) W3f[i] = (_Float16)W3[i];
}

// ---------------------------------------------------------------------------
// FPS v5: 2 waves x 16 pts/lane (state fits arch VGPRs -> no AGPR demotion).
// Update via packed-f32 asm (exact mul/add). Two-phase split-u32 reduce:
//   A) value: f32 fmax tree + 6-step DPP + readlane -> wave max (exact bits)
//   B) index: per-point equality vs wave max, inline-const J-keys, max-domain
//      n-key (2047-n) tree + DPP  -> first-occurrence argmax (min n)
// Cross-wave merge: lane63 of each wave writes {vmax_bits, nkey} to LDS,
// one barrier (parity double-buffered), lexicographic max. Centroid fetched
// from a 32KB LDS float4 copy at a uniform address (broadcast). Centroids
// staged in LDS, dumped once at the end. Selection is bit-identical to ref.
// ---------------------------------------------------------------------------
__global__ __launch_bounds__(128, 1) void fps_kernel(const float* __restrict__ xyz,
                                                     float* __restrict__ newxyz) {
  const int b = blockIdx.x, t = threadIdx.x;
  const int w = t >> 6;
  const float* X = xyz + (size_t)b * 3 * NN;
  __shared__ __align__(16) float4 XL[NN];   // 32 KB
  __shared__ float cst[3][NP];              // 6 KB
  __shared__ __align__(16) uint2 pairx[2][2];
  f32x2 px[8], py[8], pz[8], dist[8];
#pragma unroll
  for (int jj = 0; jj < 8; ++jj) {
    int n0 = t + 256 * jj, n1 = n0 + 128;
    px[jj] = f32x2{X[n0], X[n1]};
    py[jj] = f32x2{X[NN + n0], X[NN + n1]};
    pz[jj] = f32x2{X[2 * NN + n0], X[2 * NN + n1]};
    dist[jj] = f32x2{1e10f, 1e10f};
    XL[n0] = make_float4(px[jj].x, py[jj].x, pz[jj].x, 0.f);
    XL[n1] = make_float4(px[jj].y, py[jj].y, pz[jj].y, 0.f);
  }
  float cx = X[0], cy = X[NN], cz = X[2 * NN];
  const unsigned kb = 2047u - (unsigned)t;  // n-key base
  __syncthreads();
  int buf = 0;
  for (int i = 0; i < NP; ++i) {
    if (t == 0) {
      cst[0][i] = cx;
      cst[1][i] = cy;
      cst[2][i] = cz;
    }
    const f32x2 ncx = f32x2{-cx, -cx}, ncy = f32x2{-cy, -cy}, ncz = f32x2{-cz, -cz};
    // --- update dists (packed, exact) + per-pair value fold ---
    float hm[8];
#pragma unroll
    for (int jj = 0; jj < 8; ++jj) {
      f32x2 dx = pk_add(px[jj], ncx);
      f32x2 dy = pk_add(py[jj], ncy);
      f32x2 dz = pk_add(pz[jj], ncz);
      f32x2 s = pk_add(pk_add(pk_mul(dx, dx), pk_mul(dy, dy)), pk_mul(dz, dz));
      f32x2 d = dist[jj];
      d.x = fminf(d.x, s.x);
      d.y = fminf(d.y, s.y);
      dist[jj] = d;
      hm[jj] = fmaxf(d.x, d.y);
    }
    // --- phase A: wave max value ---
    float m = fmaxf(fmaxf(fmaxf(hm[0], hm[1]), fmaxf(hm[2], hm[3])),
                    fmaxf(fmaxf(hm[4], hm[5]), fmaxf(hm[6], hm[7])));
    m = dppmaxf<0x111>(m);
    m = dppmaxf<0x112>(m);
    m = dppmaxf<0x114>(m);
    m = dppmaxf<0x118>(m);
    m = dppmaxf<0x142>(m);
    m = dppmaxf<0x143>(m);
    const float vmax =
        __int_as_float(__builtin_amdgcn_readlane(__float_as_int(m), 63));
    // --- phase B: first-occurrence argmax via max-domain keys ---
    // per point J (=0..15): jkey = (d==vmax) ? 63-J : 0   (all inline consts)
    unsigned jk = 0;
#pragma unroll
    for (int jj = 0; jj < 8; ++jj) {
      unsigned c0 = (dist[jj].x == vmax) ? (63u - 2u * jj) : 0u;
      unsigned c1 = (dist[jj].y == vmax) ? (63u - (2u * jj + 1u)) : 0u;
      unsigned c = c0 > c1 ? c0 : c1;
      jk = jk > c ? jk : c;
    }
    // lane n-key: 2047-n = kb - 128*jmin, jmin = 63-jk; no-match (jk<48) -> 0
    unsigned nk = (jk >= 48u) ? (kb - ((63u - jk) << 7)) : 0u;
    nk = dppmaxu<0x111>(nk);
    nk = dppmaxu<0x112>(nk);
    nk = dppmaxu<0x114>(nk);
    nk = dppmaxu<0x118>(nk);
    nk = dppmaxu<0x142>(nk);
    nk = dppmaxu<0x143>(nk);
    // --- cross-wave merge (one barrier, parity double-buffer) ---
    if ((t & 63) == 63) pairx[buf][w] = make_uint2(__float_as_uint(m), nk);
    __syncthreads();
    uint4 pr = *(const uint4*)&pairx[buf][0];  // {v0,nk0,v1,nk1}
    bool take1 = (pr.z > pr.x) | ((pr.z == pr.x) & (pr.w > pr.y));
    unsigned ng = 2047u - (take1 ? pr.w : pr.y);
    float4 c = XL[ng];  // uniform address -> LDS broadcast
    cx = c.x;
    cy = c.y;
    cz = c.z;
    buf ^= 1;
  }
  __syncthreads();
  for (int i = t; i < NP; i += 128) {
    newxyz[b * 3 * NP + i] = cst[0][i];
    newxyz[b * 3 * NP + NP + i] = cst[1][i];
    newxyz[b * 3 * NP + 2 * NP + i] = cst[2][i];
  }
}

// ---------------------------------------------------------------------------
// Ball query (unchanged, bit-exact).
// ---------------------------------------------------------------------------
__global__ __launch_bounds__(256) void ball_kernel(const float* __restrict__ xyz,
                                                   const float* __restrict__ newxyz,
                                                   int* __restrict__ idx) {
  const int b = blockIdx.x;
  const int s = blockIdx.y * 4 + (threadIdx.x >> 6);
  const int lane = threadIdx.x & 63;
  const float* X = xyz + (size_t)b * 3 * NN;
  const float cx = newxyz[b * 3 * NP + s];
  const float cy = newxyz[b * 3 * NP + NP + s];
  const float cz = newxyz[b * 3 * NP + 2 * NP + s];
  int* row = idx + ((size_t)(b * NP + s)) * NS;
  const float r2 = (float)(0.2 * 0.2);
  int total = 0, first = 0;
  bool havefirst = false;
  for (int c0 = 0; c0 < NN; c0 += 64) {
    int n = c0 + lane;
    float d2 = sqdist(X[n] - cx, X[NN + n] - cy, X[2 * NN + n] - cz);
    bool hit = d2 < r2;
    unsigned long long mask = __ballot(hit);
    if (!havefirst && mask) {
      first = c0 + __builtin_ctzll(mask);
      havefirst = true;
    }
    if (hit) {
      int pos = total + (int)__popcll(mask & ((1ull << lane) - 1ull));
      if (pos < NS) row[pos] = n;
    }
    total += (int)__popcll(mask);
    if (total >= NS) break;
  }
  if (total < NS && lane >= total && lane < NS) row[lane] = first;
}

// ---------------------------------------------------------------------------
// MFMA MLP (unchanged): 128 cols/block (4 s), f16 activations in LDS [col][k],
// waves split output rows, fused maxpool, fp32 accumulate.
// ---------------------------------------------------------------------------
#define HSTR 104   // hT stride in f16 (96 padded)
#define A1STR 72   // a1 stride (64 padded)
#define A2STR 136  // a2 stride (128 padded)
#define A1OFF 17408

__global__ __launch_bounds__(256) void mlp_kernel(
    const float* __restrict__ xyzT, const _Float16* __restrict__ featF,
    const int* __restrict__ idx, const float* __restrict__ newxyz,
    const _Float16* __restrict__ W1f, const float* __restrict__ b1,
    const _Float16* __restrict__ W2f, const float* __restrict__ b2,
    const _Float16* __restrict__ W3f, const float* __restrict__ b3, float* __restrict__ out) {
  __shared__ _Float16 smem[17408 + 9216];  // 52 KB: h/a2 alias region + a1
  _Float16* hT = smem;
  _Float16* a1T = smem + A1OFF;
  const int b = blockIdx.x;
  const int s0 = blockIdx.y * 4;
  const int t = threadIdx.x;
  const int lane = t & 63, w = t >> 6;

  // ---- gather: hT[128 cols][96 k] (k: 0..63 feat, 64..66 relxyz, 67..95 zero)
  {
    const int col = t & 127, hf = t >> 7;
    const int s = s0 + (col >> 5), k = col & 31;
    const int n = idx[((size_t)(b * NP + s)) * NS + k];
    const _Float16* F = featF + (size_t)(b * NN + n) * NC;
#pragma unroll
    for (int j = 0; j < 4; ++j) {
      int p = hf * 4 + j;
      *(f16x8*)(&hT[col * HSTR + p * 8]) = *(const f16x8*)(F + p * 8);
    }
    if (hf == 0) {
      float4 pnt = ((const float4*)xyzT)[(size_t)b * NN + n];
      float cx = newxyz[b * 3 * NP + s];
      float cy = newxyz[b * 3 * NP + NP + s];
      float cz = newxyz[b * 3 * NP + 2 * NP + s];
      f16x8 v = {};
      v[0] = (_Float16)(pnt.x - cx);
      v[1] = (_Float16)(pnt.y - cy);
      v[2] = (_Float16)(pnt.z - cz);
      *(f16x8*)(&hT[col * HSTR + 64]) = v;
    } else {
      f16x8 z = {};
      *(f16x8*)(&hT[col * HSTR + 72]) = z;
      *(f16x8*)(&hT[col * HSTR + 80]) = z;
      *(f16x8*)(&hT[col * HSTR + 88]) = z;
    }
  }
  __syncthreads();

  const int cl = lane & 15;  // A row / B col within tile
  const int kg = lane >> 4;  // k-group; D row group

  // ---- layer 1: K=96, O=64; wave w owns rows w*16..+15
  {
    f32x4 acc[8];
    {
      f32x4 bb = *(const f32x4*)(b1 + w * 16 + kg * 4);
#pragma unroll
      for (int ct = 0; ct < 8; ++ct) acc[ct] = bb;
    }
#pragma unroll
    for (int ks = 0; ks < 3; ++ks) {
      f16x8 A = *(const f16x8*)(W1f + (w * 16 + cl) * 96 + ks * 32 + kg * 8);
#pragma unroll
      for (int ct = 0; ct < 8; ++ct) {
        f16x8 B = *(const f16x8*)(&hT[(ct * 16 + cl) * HSTR + ks * 32 + kg * 8]);
        acc[ct] = __builtin_amdgcn_mfma_f32_16x16x32_f16(A, B, acc[ct], 0, 0, 0);
      }
    }
#pragma unroll
    for (int ct = 0; ct < 8; ++ct) {
      f16x4 v;
#pragma unroll
      for (int i2 = 0; i2 < 4; ++i2) v[i2] = (_Float16)fmaxf(acc[ct][i2], 0.f);
      *(f16x4*)(&a1T[(ct * 16 + cl) * A1STR + w * 16 + kg * 4]) = v;
    }
  }
  __syncthreads();

  // ---- layer 2: K=64, O=128; wave w owns rows w*32..+31 (a2 aliases h)
  {
    f32x4 acc[2][8];
#pragma unroll
    for (int r = 0; r < 2; ++r) {
      f32x4 bb = *(const f32x4*)(b2 + w * 32 + r * 16 + kg * 4);
#pragma unroll
      for (int ct = 0; ct < 8; ++ct) acc[r][ct] = bb;
    }
#pragma unroll
    for (int ks = 0; ks < 2; ++ks) {
      f16x8 A0 = *(const f16x8*)(W2f + (w * 32 + cl) * 64 + ks * 32 + kg * 8);
      f16x8 A1 = *(const f16x8*)(W2f + (w * 32 + 16 + cl) * 64 + ks * 32 + kg * 8);
#pragma unroll
      for (int ct = 0; ct < 8; ++ct) {
        f16x8 B = *(const f16x8*)(&a1T[(ct * 16 + cl) * A1STR + ks * 32 + kg * 8]);
        acc[0][ct] = __builtin_amdgcn_mfma_f32_16x16x32_f16(A0, B, acc[0][ct], 0, 0, 0);
        acc[1][ct] = __builtin_amdgcn_mfma_f32_16x16x32_f16(A1, B, acc[1][ct], 0, 0, 0);
      }
    }
#pragma unroll
    for (int r = 0; r < 2; ++r)
#pragma unroll
      for (int ct = 0; ct < 8; ++ct) {
        f16x4 v;
#pragma unroll
        for (int i2 = 0; i2 < 4; ++i2) v[i2] = (_Float16)fmaxf(acc[r][ct][i2], 0.f);
        *(f16x4*)(&hT[(ct * 16 + cl) * A2STR + w * 32 + r * 16 + kg * 4]) = v;
      }
  }
  __syncthreads();

  // ---- layer 3: K=128, O=256; wave w owns rows w*64..+63; fused maxpool
  float* out2 = out + NB * 3 * NP;
#pragma unroll
  for (int rh = 0; rh < 2; ++rh) {
    f32x4 acc[2][8];
#pragma unroll
    for (int r = 0; r < 2; ++r) {
      f32x4 bb = *(const f32x4*)(b3 + w * 64 + rh * 32 + r * 16 + kg * 4);
#pragma unroll
      for (int ct = 0; ct < 8; ++ct) acc[r][ct] = bb;
    }
#pragma unroll
    for (int ks = 0; ks < 4; ++ks) {
      f16x8 A0 = *(const f16x8*)(W3f + (w * 64 + rh * 32 + cl) * 128 + ks * 32 + kg * 8);
      f16x8 A1 = *(const f16x8*)(W3f + (w * 64 + rh * 32 + 16 + cl) * 128 + ks * 32 + kg * 8);
#pragma unroll
      for (int ct = 0; ct < 8; ++ct) {
        f16x8 B = *(const f16x8*)(&hT[(ct * 16 + cl) * A2STR + ks * 32 + kg * 8]);
        acc[0][ct] = __builtin_amdgcn_mfma_f32_16x16x32_f16(A0, B, acc[0][ct], 0, 0, 0);
        acc[1][ct] = __builtin_amdgcn_mfma_f32_16x16x32_f16(A1, B, acc[1][ct], 0, 0, 0);
      }
    }
#pragma unroll
    for (int r = 0; r < 2; ++r)
#pragma unroll
      for (int sl = 0; sl < 4; ++sl) {
        float vv[4];
#pragma unroll
        for (int i2 = 0; i2 < 4; ++i2) {
          float m0 = fmaxf(acc[r][sl * 2][i2], 0.f);
          float m1 = fmaxf(acc[r][sl * 2 + 1][i2], 0.f);
          float mv = fmaxf(m0, m1);
          mv = fmaxf(mv, __shfl_xor(mv, 1, 64));
          mv = fmaxf(mv, __shfl_xor(mv, 2, 64));
          mv = fmaxf(mv, __shfl_xor(mv, 4, 64));
          mv = fmaxf(mv, __shfl_xor(mv, 8, 64));
          vv[i2] = mv;
        }
        if (cl == 0) {
          int ob = w * 64 + rh * 32 + r * 16 + kg * 4;
#pragma unroll
          for (int i2 = 0; i2 < 4; ++i2)
            out2[((size_t)(b * 256 + ob + i2)) * NP + s0 + sl] = vv[i2];
        }
      }
  }
}

extern "C" void kernel_launch(void* const* d_in, const int* in_sizes, int n_in, void* d_out,
                              int out_size, void* d_ws, size_t ws_size, hipStream_t stream) {
  const float* xyz = (const float*)d_in[0];
  const float* feat = (const float*)d_in[1];
  const float* W1 = (const float*)d_in[2];
  const float* b1 = (const float*)d_in[3];
  const float* W2 = (const float*)d_in[4];
  const float* b2 = (const float*)d_in[5];
  const float* W3 = (const float*)d_in[6];
  const float* b3 = (const float*)d_in[7];
  float* out = (float*)d_out;
  char* ws = (char*)d_ws;
  float* xyzT = (float*)ws;                    // 512 KB
  _Float16* featF = (_Float16*)(ws + 524288);  // 4 MB
  int* idx = (int*)(ws + 4718592);             // 1 MB
  _Float16* W1f = (_Float16*)(ws + 5767168);   // 12 KB
  _Float16* W2f = (_Float16*)(ws + 5779456);   // 16 KB
  _Float16* W3f = (_Float16*)(ws + 5795840);   // 64 KB

  hipLaunchKernelGGL(prep_kernel, dim3(NB, 32), dim3(256), 0, stream, feat, xyz, featF, xyzT);
  hipLaunchKernelGGL(wconv_kernel, dim3(128), dim3(256), 0, stream, W1, W2, W3, W1f, W2f, W3f);
  hipLaunchKernelGGL(fps_kernel, dim3(NB), dim3(128), 0, stream, xyz, out);
  hipLaunchKernelGGL(ball_kernel, dim3(NB, 128), dim3(256), 0, stream, xyz, out, idx);
  hipLaunchKernelGGL(mlp_kernel, dim3(NB, 128), dim3(256), 0, stream, xyzT, featF, idx, out, W1f,
                     b1, W2f, b2, W3f, b3, out);
}

// Round 7
// 377.955 us; speedup vs baseline: 2.5485x; 1.0475x over previous
//
#include <hip/hip_runtime.h>

#define NB 16
#define NN 2048
#define NP 512
#define NS 32
#define NC 64

typedef _Float16 f16x8 __attribute__((ext_vector_type(8)));
typedef _Float16 f16x4 __attribute__((ext_vector_type(4)));
typedef float f32x4 __attribute__((ext_vector_type(4)));
typedef float f32x2 __attribute__((ext_vector_type(2)));

// d2 with explicit rounding (no FMA contraction) to bit-match the reference
__device__ __forceinline__ float sqdist(float dx, float dy, float dz) {
  return __fadd_rn(__fadd_rn(__fmul_rn(dx, dx), __fmul_rn(dy, dy)), __fmul_rn(dz, dz));
}

// packed f32 add/mul via inline asm: separate mul and add instructions, so the
// compiler can never contract them into FMA -> bit-exact vs the reference.
__device__ __forceinline__ f32x2 pk_add(f32x2 a, f32x2 b) {
  f32x2 d;
  asm("v_pk_add_f32 %0, %1, %2" : "=v"(d) : "v"(a), "v"(b));
  return d;
}
__device__ __forceinline__ f32x2 pk_mul(f32x2 a, f32x2 b) {
  f32x2 d;
  asm("v_pk_mul_f32 %0, %1, %2" : "=v"(d) : "v"(a), "v"(b));
  return d;
}

template <int CTRL>
__device__ __forceinline__ float dppmaxf(float m) {
  int t = __builtin_amdgcn_update_dpp(0, __float_as_int(m), CTRL, 0xf, 0xf, true);
  return fmaxf(m, __int_as_float(t));  // 0-fill safe: all values >= 0
}

// ---------------------------------------------------------------------------
// Fused front kernel: block roles by blockIdx.x
//   [0,16)    : FPS for batch b = blockIdx.x        (256 thr = 4 waves)
//   [16,528)  : prep transpose tile (b, n0)          (featF f16 + xyzT)
//   528       : weight f16 conversion
// FPS v6: 4 waves x 8 pts/lane. Packed-f32 exact update; value wave-max via
// 6-step DPP; index via 8 ballots + scalar first-set scan (first-occurrence
// = min n exact); cross-wave merge via one 32B LDS read + 3 lex compares;
// centroid broadcast via uniform ds_read_b128 from LDS xyz copy.
// ---------------------------------------------------------------------------
__global__ __launch_bounds__(256, 1) void front_kernel(
    const float* __restrict__ xyz, const float* __restrict__ feat,
    const float* __restrict__ W1, const float* __restrict__ W2, const float* __restrict__ W3,
    float* __restrict__ newxyz, _Float16* __restrict__ featF, float* __restrict__ xyzT,
    _Float16* __restrict__ W1f, _Float16* __restrict__ W2f, _Float16* __restrict__ W3f) {
  __shared__ __align__(16) char sm[39040];
  const int bid = blockIdx.x;
  const int t = threadIdx.x;

  if (bid >= 16) {
    if (bid == 528) {
      // ---- wconv role ----
      for (int i = t; i < 256 * 128; i += 256) {
        if (i < 64 * 96) {
          int o = i / 96, k = i - o * 96;
          float v = (k < 64) ? W1[o * 67 + 3 + k] : ((k < 67) ? W1[o * 67 + (k - 64)] : 0.f);
          W1f[i] = (_Float16)v;
        }
        if (i < 128 * 64) W2f[i] = (_Float16)W2[i];
        W3f[i] = (_Float16)W3[i];
      }
      return;
    }
    // ---- prep role ----
    float(*tile)[65] = (float(*)[65])sm;
    const int pb = bid - 16;
    const int b = pb >> 5;
    const int n0 = (pb & 31) * 64;
    const int g = t >> 6, l = t & 63;
    if (g == 0) {
      int n = n0 + l;
      float4 q;
      q.x = xyz[(size_t)b * 3 * NN + n];
      q.y = xyz[(size_t)b * 3 * NN + NN + n];
      q.z = xyz[(size_t)b * 3 * NN + 2 * NN + n];
      q.w = 0.f;
      ((float4*)xyzT)[(size_t)b * NN + n] = q;
    }
#pragma unroll
    for (int r = 0; r < 16; ++r) {
      int c = g * 16 + r;
      tile[c][l] = feat[((size_t)b * NC + c) * NN + n0 + l];
    }
    __syncthreads();
#pragma unroll
    for (int r = 0; r < 16; ++r) {
      int nl = g * 16 + r;
      featF[((size_t)(b * NN + n0 + nl)) * NC + l] = (_Float16)tile[l][nl];
    }
    return;
  }

  // ---- FPS role ----
  const int b = bid;
  const int w = t >> 6;
  const float* X = xyz + (size_t)b * 3 * NN;
  float4* XL = (float4*)sm;                       // 32768 B
  float* cst = (float*)(sm + 32768);              // 3*512*4 = 6144 B
  uint2* ck = (uint2*)(sm + 32768 + 6144);        // [2][4] = 64 B

  f32x2 px[4], py[4], pz[4], dist[4];
#pragma unroll
  for (int jj = 0; jj < 4; ++jj) {
    int n0 = t + 256 * jj, n1 = n0 + 1024;
    px[jj] = f32x2{X[n0], X[n1]};
    py[jj] = f32x2{X[NN + n0], X[NN + n1]};
    pz[jj] = f32x2{X[2 * NN + n0], X[2 * NN + n1]};
    dist[jj] = f32x2{1e10f, 1e10f};
    XL[n0] = make_float4(px[jj].x, py[jj].x, pz[jj].x, 0.f);
    XL[n1] = make_float4(px[jj].y, py[jj].y, pz[jj].y, 0.f);
  }
  float cx = X[0], cy = X[NN], cz = X[2 * NN];
  __syncthreads();
  int buf = 0;
  for (int i = 0; i < NP; ++i) {
    if (t == 0) {
      cst[i] = cx;
      cst[NP + i] = cy;
      cst[2 * NP + i] = cz;
    }
    const f32x2 ncx = f32x2{-cx, -cx}, ncy = f32x2{-cy, -cy}, ncz = f32x2{-cz, -cz};
    float hm[4];
#pragma unroll
    for (int jj = 0; jj < 4; ++jj) {
      f32x2 dx = pk_add(px[jj], ncx);
      f32x2 dy = pk_add(py[jj], ncy);
      f32x2 dz = pk_add(pz[jj], ncz);
      f32x2 s = pk_add(pk_add(pk_mul(dx, dx), pk_mul(dy, dy)), pk_mul(dz, dz));
      f32x2 d = dist[jj];
      d.x = fminf(d.x, s.x);
      d.y = fminf(d.y, s.y);
      dist[jj] = d;
      hm[jj] = fmaxf(d.x, d.y);
    }
    // phase A: wave max value (exact bits preserved by fmax chain)
    float m = fmaxf(fmaxf(hm[0], hm[1]), fmaxf(hm[2], hm[3]));
    m = dppmaxf<0x111>(m);
    m = dppmaxf<0x112>(m);
    m = dppmaxf<0x114>(m);
    m = dppmaxf<0x118>(m);
    m = dppmaxf<0x142>(m);
    m = dppmaxf<0x143>(m);
    const float vmax = __int_as_float(__builtin_amdgcn_readlane(__float_as_int(m), 63));
    // phase B: ballot per point-group, scalar first-set scan (min n)
    unsigned long long mm[8];
#pragma unroll
    for (int jj = 0; jj < 4; ++jj) {
      mm[jj] = __ballot(dist[jj].x == vmax);
      mm[4 + jj] = __ballot(dist[jj].y == vmax);
    }
    unsigned nw = 0;
#pragma unroll
    for (int q = 7; q >= 0; --q)
      if (mm[q]) nw = 256u * (unsigned)q + (unsigned)(w << 6) + (unsigned)__builtin_ctzll(mm[q]);
    if ((t & 63) == 0) ck[buf * 4 + w] = make_uint2(__float_as_uint(vmax), nw);
    __syncthreads();
    // cross-wave merge: 32B = two independent b128 reads, 3 lex compares.
    // dist >= 0 -> float order == unsigned order on the bits.
    uint4 c01 = *(const uint4*)&ck[buf * 4 + 0];
    uint4 c23 = *(const uint4*)&ck[buf * 4 + 2];
    unsigned v = c01.x, n = c01.y;
    if (c01.z > v || (c01.z == v && c01.w < n)) { v = c01.z; n = c01.w; }
    if (c23.x > v || (c23.x == v && c23.y < n)) { v = c23.x; n = c23.y; }
    if (c23.z > v || (c23.z == v && c23.w < n)) { v = c23.z; n = c23.w; }
    float4 c = XL[n];  // uniform address -> LDS broadcast
    cx = c.x;
    cy = c.y;
    cz = c.z;
    buf ^= 1;
  }
  __syncthreads();
  for (int i = t; i < NP; i += 256) {
    newxyz[b * 3 * NP + i] = cst[i];
    newxyz[b * 3 * NP + NP + i] = cst[NP + i];
    newxyz[b * 3 * NP + 2 * NP + i] = cst[2 * NP + i];
  }
}

// ---------------------------------------------------------------------------
// Ball query (unchanged, bit-exact).
// ---------------------------------------------------------------------------
__global__ __launch_bounds__(256) void ball_kernel(const float* __restrict__ xyz,
                                                   const float* __restrict__ newxyz,
                                                   int* __restrict__ idx) {
  const int b = blockIdx.x;
  const int s = blockIdx.y * 4 + (threadIdx.x >> 6);
  const int lane = threadIdx.x & 63;
  const float* X = xyz + (size_t)b * 3 * NN;
  const float cx = newxyz[b * 3 * NP + s];
  const float cy = newxyz[b * 3 * NP + NP + s];
  const float cz = newxyz[b * 3 * NP + 2 * NP + s];
  int* row = idx + ((size_t)(b * NP + s)) * NS;
  const float r2 = (float)(0.2 * 0.2);
  int total = 0, first = 0;
  bool havefirst = false;
  for (int c0 = 0; c0 < NN; c0 += 64) {
    int n = c0 + lane;
    float d2 = sqdist(X[n] - cx, X[NN + n] - cy, X[2 * NN + n] - cz);
    bool hit = d2 < r2;
    unsigned long long mask = __ballot(hit);
    if (!havefirst && mask) {
      first = c0 + __builtin_ctzll(mask);
      havefirst = true;
    }
    if (hit) {
      int pos = total + (int)__popcll(mask & ((1ull << lane) - 1ull));
      if (pos < NS) row[pos] = n;
    }
    total += (int)__popcll(mask);
    if (total >= NS) break;
  }
  if (total < NS && lane >= total && lane < NS) row[lane] = first;
}

// ---------------------------------------------------------------------------
// MFMA MLP (unchanged): 128 cols/block (4 s), f16 activations in LDS [col][k],
// waves split output rows, fused maxpool, fp32 accumulate.
// ---------------------------------------------------------------------------
#define HSTR 104   // hT stride in f16 (96 padded)
#define A1STR 72   // a1 stride (64 padded)
#define A2STR 136  // a2 stride (128 padded)
#define A1OFF 17408

__global__ __launch_bounds__(256) void mlp_kernel(
    const float* __restrict__ xyzT, const _Float16* __restrict__ featF,
    const int* __restrict__ idx, const float* __restrict__ newxyz,
    const _Float16* __restrict__ W1f, const float* __restrict__ b1,
    const _Float16* __restrict__ W2f, const float* __restrict__ b2,
    const _Float16* __restrict__ W3f, const float* __restrict__ b3, float* __restrict__ out) {
  __shared__ _Float16 smem[17408 + 9216];  // 52 KB: h/a2 alias region + a1
  _Float16* hT = smem;
  _Float16* a1T = smem + A1OFF;
  const int b = blockIdx.x;
  const int s0 = blockIdx.y * 4;
  const int t = threadIdx.x;
  const int lane = t & 63, w = t >> 6;

  // ---- gather: hT[128 cols][96 k] (k: 0..63 feat, 64..66 relxyz, 67..95 zero)
  {
    const int col = t & 127, hf = t >> 7;
    const int s = s0 + (col >> 5), k = col & 31;
    const int n = idx[((size_t)(b * NP + s)) * NS + k];
    const _Float16* F = featF + (size_t)(b * NN + n) * NC;
#pragma unroll
    for (int j = 0; j < 4; ++j) {
      int p = hf * 4 + j;
      *(f16x8*)(&hT[col * HSTR + p * 8]) = *(const f16x8*)(F + p * 8);
    }
    if (hf == 0) {
      float4 pnt = ((const float4*)xyzT)[(size_t)b * NN + n];
      float cx = newxyz[b * 3 * NP + s];
      float cy = newxyz[b * 3 * NP + NP + s];
      float cz = newxyz[b * 3 * NP + 2 * NP + s];
      f16x8 v = {};
      v[0] = (_Float16)(pnt.x - cx);
      v[1] = (_Float16)(pnt.y - cy);
      v[2] = (_Float16)(pnt.z - cz);
      *(f16x8*)(&hT[col * HSTR + 64]) = v;
    } else {
      f16x8 z = {};
      *(f16x8*)(&hT[col * HSTR + 72]) = z;
      *(f16x8*)(&hT[col * HSTR + 80]) = z;
      *(f16x8*)(&hT[col * HSTR + 88]) = z;
    }
  }
  __syncthreads();

  const int cl = lane & 15;  // A row / B col within tile
  const int kg = lane >> 4;  // k-group; D row group

  // ---- layer 1: K=96, O=64; wave w owns rows w*16..+15
  {
    f32x4 acc[8];
    {
      f32x4 bb = *(const f32x4*)(b1 + w * 16 + kg * 4);
#pragma unroll
      for (int ct = 0; ct < 8; ++ct) acc[ct] = bb;
    }
#pragma unroll
    for (int ks = 0; ks < 3; ++ks) {
      f16x8 A = *(const f16x8*)(W1f + (w * 16 + cl) * 96 + ks * 32 + kg * 8);
#pragma unroll
      for (int ct = 0; ct < 8; ++ct) {
        f16x8 B = *(const f16x8*)(&hT[(ct * 16 + cl) * HSTR + ks * 32 + kg * 8]);
        acc[ct] = __builtin_amdgcn_mfma_f32_16x16x32_f16(A, B, acc[ct], 0, 0, 0);
      }
    }
#pragma unroll
    for (int ct = 0; ct < 8; ++ct) {
      f16x4 v;
#pragma unroll
      for (int i2 = 0; i2 < 4; ++i2) v[i2] = (_Float16)fmaxf(acc[ct][i2], 0.f);
      *(f16x4*)(&a1T[(ct * 16 + cl) * A1STR + w * 16 + kg * 4]) = v;
    }
  }
  __syncthreads();

  // ---- layer 2: K=64, O=128; wave w owns rows w*32..+31 (a2 aliases h)
  {
    f32x4 acc[2][8];
#pragma unroll
    for (int r = 0; r < 2; ++r) {
      f32x4 bb = *(const f32x4*)(b2 + w * 32 + r * 16 + kg * 4);
#pragma unroll
      for (int ct = 0; ct < 8; ++ct) acc[r][ct] = bb;
    }
#pragma unroll
    for (int ks = 0; ks < 2; ++ks) {
      f16x8 A0 = *(const f16x8*)(W2f + (w * 32 + cl) * 64 + ks * 32 + kg * 8);
      f16x8 A1 = *(const f16x8*)(W2f + (w * 32 + 16 + cl) * 64 + ks * 32 + kg * 8);
#pragma unroll
      for (int ct = 0; ct < 8; ++ct) {
        f16x8 B = *(const f16x8*)(&a1T[(ct * 16 + cl) * A1STR + ks * 32 + kg * 8]);
        acc[0][ct] = __builtin_amdgcn_mfma_f32_16x16x32_f16(A0, B, acc[0][ct], 0, 0, 0);
        acc[1][ct] = __builtin_amdgcn_mfma_f32_16x16x32_f16(A1, B, acc[1][ct], 0, 0, 0);
      }
    }
#pragma unroll
    for (int r = 0; r < 2; ++r)
#pragma unroll
      for (int ct = 0; ct < 8; ++ct) {
        f16x4 v;
#pragma unroll
        for (int i2 = 0; i2 < 4; ++i2) v[i2] = (_Float16)fmaxf(acc[r][ct][i2], 0.f);
        *(f16x4*)(&hT[(ct * 16 + cl) * A2STR + w * 32 + r * 16 + kg * 4]) = v;
      }
  }
  __syncthreads();

  // ---- layer 3: K=128, O=256; wave w owns rows w*64..+63; fused maxpool
  float* out2 = out + NB * 3 * NP;
#pragma unroll
  for (int rh = 0; rh < 2; ++rh) {
    f32x4 acc[2][8];
#pragma unroll
    for (int r = 0; r < 2; ++r) {
      f32x4 bb = *(const f32x4*)(b3 + w * 64 + rh * 32 + r * 16 + kg * 4);
#pragma unroll
      for (int ct = 0; ct < 8; ++ct) acc[r][ct] = bb;
    }
#pragma unroll
    for (int ks = 0; ks < 4; ++ks) {
      f16x8 A0 = *(const f16x8*)(W3f + (w * 64 + rh * 32 + cl) * 128 + ks * 32 + kg * 8);
      f16x8 A1 = *(const f16x8*)(W3f + (w * 64 + rh * 32 + 16 + cl) * 128 + ks * 32 + kg * 8);
#pragma unroll
      for (int ct = 0; ct < 8; ++ct) {
        f16x8 B = *(const f16x8*)(&hT[(ct * 16 + cl) * A2STR + ks * 32 + kg * 8]);
        acc[0][ct] = __builtin_amdgcn_mfma_f32_16x16x32_f16(A0, B, acc[0][ct], 0, 0, 0);
        acc[1][ct] = __builtin_amdgcn_mfma_f32_16x16x32_f16(A1, B, acc[1][ct], 0, 0, 0);
      }
    }
#pragma unroll
    for (int r = 0; r < 2; ++r)
#pragma unroll
      for (int sl = 0; sl < 4; ++sl) {
        float vv[4];
#pragma unroll
        for (int i2 = 0; i2 < 4; ++i2) {
          float m0 = fmaxf(acc[r][sl * 2][i2], 0.f);
          float m1 = fmaxf(acc[r][sl * 2 + 1][i2], 0.f);
          float mv = fmaxf(m0, m1);
          mv = fmaxf(mv, __shfl_xor(mv, 1, 64));
          mv = fmaxf(mv, __shfl_xor(mv, 2, 64));
          mv = fmaxf(mv, __shfl_xor(mv, 4, 64));
          mv = fmaxf(mv, __shfl_xor(mv, 8, 64));
          vv[i2] = mv;
        }
        if (cl == 0) {
          int ob = w * 64 + rh * 32 + r * 16 + kg * 4;
#pragma unroll
          for (int i2 = 0; i2 < 4; ++i2)
            out2[((size_t)(b * 256 + ob + i2)) * NP + s0 + sl] = vv[i2];
        }
      }
  }
}

extern "C" void kernel_launch(void* const* d_in, const int* in_sizes, int n_in, void* d_out,
                              int out_size, void* d_ws, size_t ws_size, hipStream_t stream) {
  const float* xyz = (const float*)d_in[0];
  const float* feat = (const float*)d_in[1];
  const float* W1 = (const float*)d_in[2];
  const float* b1 = (const float*)d_in[3];
  const float* W2 = (const float*)d_in[4];
  const float* b2 = (const float*)d_in[5];
  const float* W3 = (const float*)d_in[6];
  const float* b3 = (const float*)d_in[7];
  float* out = (float*)d_out;
  char* ws = (char*)d_ws;
  float* xyzT = (float*)ws;                    // 512 KB
  _Float16* featF = (_Float16*)(ws + 524288);  // 4 MB
  int* idx = (int*)(ws + 4718592);             // 1 MB
  _Float16* W1f = (_Float16*)(ws + 5767168);   // 12 KB
  _Float16* W2f = (_Float16*)(ws + 5779456);   // 16 KB
  _Float16* W3f = (_Float16*)(ws + 5795840);   // 64 KB

  hipLaunchKernelGGL(front_kernel, dim3(529), dim3(256), 0, stream, xyz, feat, W1, W2, W3, out,
                     featF, xyzT, W1f, W2f, W3f);
  hipLaunchKernelGGL(ball_kernel, dim3(NB, 128), dim3(256), 0, stream, xyz, out, idx);
  hipLaunchKernelGGL(mlp_kernel, dim3(NB, 128), dim3(256), 0, stream, xyzT, featF, idx, out, W1f,
                     b1, W2f, b2, W3f, b3, out);
}